// Round 7
// baseline (568.366 us; speedup 1.0000x reference)
//
#include <hip/hip_runtime.h>

typedef unsigned short u16;
typedef unsigned int u32;

#define BATCH 8
#define NNODE 2048
#define FEAT  128

__device__ __forceinline__ float b2f(u16 b) {
  union { u32 u; float f; } x;
  x.u = ((u32)b) << 16;
  return x.f;
}
__device__ __forceinline__ u16 f2b(float f) {
  union { float f; u32 u; } x;
  x.f = f;
  return (u16)((x.u + 0x7fffu + ((x.u >> 16) & 1u)) >> 16);
}

// ---------------------------------------------------------------------------
// Fully fused GraphSAGE layer, VALU-only. ALL inputs f32, output f32.
// Forensic basis: r4 (bf16 reads) -> NaN (f32 data read as bf16 mints NaNs);
// r5/r6 (f32 reads, bf16-packed stores) -> absmax == max|ref| because only
// half the 8MB f32 output buffer was written (rest memset 0). This round
// changes ONLY the store format of the provably-running r6 kernel: f32 out.
//
// Block = 256 threads handles 16 output rows of one batch.
//   thread t: feature pair fp = t&63 (features 2fp, 2fp+1),
//             row group rg = t>>6 (rows rg*4 .. rg*4+3).
// Phase 1: agg[r][f] = (sum_j adj[i0+r][j] * h[j][f]) / N, h staged in LDS
//          as packed bf16 pairs (error ~0.4% relative, ~1e-5 absolute on agg;
//          threshold is 1.26e-2 absolute -> safe).
// Phase 2: out = relu(h@Ws + agg@Wn + bs + bn) in full f32, then row
//          L2-normalize, f32 store.
// ---------------------------------------------------------------------------
__global__ __launch_bounds__(256) void sage_fused_kernel(
    const float* __restrict__ h,    // (B, N, F) f32
    const float* __restrict__ adj,  // (B, N, N) f32 {0,1}
    const float* __restrict__ Ws,   // (F, F) f32
    const float* __restrict__ bs,   // (F,) f32
    const float* __restrict__ Wn,   // (F, F) f32
    const float* __restrict__ bn,   // (F,) f32
    float* __restrict__ out)        // (B, N, F) f32
{
  __shared__ u32 sHu[64 * 128];     // 32 KB: h tile as bf16 pairs, 128 j x 64 fp
  __shared__ float sAgg[16 * 128];  // 8 KB: aggregated tile (fp32)
  __shared__ float sInv[16];

  const int tid = threadIdx.x;
  const int fp = tid & 63;        // feature pair 0..63
  const int rg = tid >> 6;        // row group 0..3
  const int b  = blockIdx.x >> 7; // 128 blocks per batch
  const int i0 = (blockIdx.x & 127) * 16;

  const float* hB   = h + (size_t)b * NNODE * FEAT;
  const float* adjR = adj + ((size_t)b * NNODE + (size_t)(i0 + rg * 4)) * NNODE;

  float acc[4][2];
#pragma unroll
  for (int rr = 0; rr < 4; rr++) { acc[rr][0] = 0.0f; acc[rr][1] = 0.0f; }

  // ---- phase 1: aggregate neighbors ----
  for (int jt = 0; jt < 16; jt++) {
    const int j0 = jt * 128;
    __syncthreads();
    const float2* hsrc = (const float2*)(hB + (size_t)j0 * FEAT);
#pragma unroll
    for (int it = 0; it < 32; it++) {
      float2 v = hsrc[it * 256 + tid];
      sHu[it * 256 + tid] = (u32)f2b(v.x) | ((u32)f2b(v.y) << 16);
    }
    __syncthreads();

    for (int jq = 0; jq < 32; jq++) {
      // adj loads are wave-uniform (rg constant per wave) -> broadcast
      float4 a0 = *(const float4*)(adjR + 0 * (size_t)NNODE + j0 + jq * 4);
      float4 a1 = *(const float4*)(adjR + 1 * (size_t)NNODE + j0 + jq * 4);
      float4 a2 = *(const float4*)(adjR + 2 * (size_t)NNODE + j0 + jq * 4);
      float4 a3 = *(const float4*)(adjR + 3 * (size_t)NNODE + j0 + jq * 4);
      float av[4][4];
      av[0][0] = a0.x; av[0][1] = a0.y; av[0][2] = a0.z; av[0][3] = a0.w;
      av[1][0] = a1.x; av[1][1] = a1.y; av[1][2] = a1.z; av[1][3] = a1.w;
      av[2][0] = a2.x; av[2][1] = a2.y; av[2][2] = a2.z; av[2][3] = a2.w;
      av[3][0] = a3.x; av[3][1] = a3.y; av[3][2] = a3.z; av[3][3] = a3.w;
#pragma unroll
      for (int e = 0; e < 4; e++) {
        u32 hu = sHu[(jq * 4 + e) * 64 + fp];
        float hlo = b2f((u16)(hu & 0xffffu));
        float hhi = b2f((u16)(hu >> 16));
#pragma unroll
        for (int rr = 0; rr < 4; rr++) {
          acc[rr][0] += av[rr][e] * hlo;
          acc[rr][1] += av[rr][e] * hhi;
        }
      }
    }
  }

  const float invN = 1.0f / (float)NNODE;
#pragma unroll
  for (int rr = 0; rr < 4; rr++) {
    sAgg[(rg * 4 + rr) * 128 + fp * 2 + 0] = acc[rr][0] * invN;
    sAgg[(rg * 4 + rr) * 128 + fp * 2 + 1] = acc[rr][1] * invN;
  }
  __syncthreads();

  // ---- phase 2: linear layers (full f32) ----
  float o[4][2];
#pragma unroll
  for (int rr = 0; rr < 4; rr++) { o[rr][0] = 0.0f; o[rr][1] = 0.0f; }

  const float2* WsU = (const float2*)Ws;
  const float2* WnU = (const float2*)Wn;
  for (int k = 0; k < 128; k++) {
    float2 wsv = WsU[k * 64 + fp];
    float2 wnv = WnU[k * 64 + fp];
#pragma unroll
    for (int rr = 0; rr < 4; rr++) {
      float hv = hB[(size_t)(i0 + rg * 4 + rr) * FEAT + k];
      float gv = sAgg[(rg * 4 + rr) * 128 + k];
      o[rr][0] += hv * wsv.x + gv * wnv.x;
      o[rr][1] += hv * wsv.y + gv * wnv.y;
    }
  }

  // ---- bias + relu, stash to LDS for row reduction ----
  float bias0 = bs[fp * 2 + 0] + bn[fp * 2 + 0];
  float bias1 = bs[fp * 2 + 1] + bn[fp * 2 + 1];
  float* sOut = (float*)sHu;   // reuse 32 KB staging buffer
  __syncthreads();
#pragma unroll
  for (int rr = 0; rr < 4; rr++) {
    float v0 = o[rr][0] + bias0; if (v0 < 0.0f) v0 = 0.0f;
    float v1 = o[rr][1] + bias1; if (v1 < 0.0f) v1 = 0.0f;
    o[rr][0] = v0; o[rr][1] = v1;
    sOut[(rg * 4 + rr) * 128 + fp * 2 + 0] = v0;
    sOut[(rg * 4 + rr) * 128 + fp * 2 + 1] = v1;
  }
  __syncthreads();
  if (tid < 16) {
    float s = 0.0f;
    for (int i = 0; i < 128; i++) {
      int ii = (i + tid * 8) & 127;            // stagger to spread LDS banks
      float v = sOut[tid * 128 + ii];
      s += v * v;
    }
    float nrm = sqrtf(s);
    if (nrm < 1e-12f) nrm = 1e-12f;
    sInv[tid] = 1.0f / nrm;
  }
  __syncthreads();

  // ---- normalize + f32 store (float2 per thread, coalesced) ----
  float2* outU = (float2*)(out + ((size_t)b * NNODE + (size_t)i0) * FEAT);
#pragma unroll
  for (int rr = 0; rr < 4; rr++) {
    int r = rg * 4 + rr;
    float scl = sInv[r];
    float2 pv;
    pv.x = o[rr][0] * scl;
    pv.y = o[rr][1] * scl;
    outU[r * 64 + fp] = pv;
  }
}

// ---------------------------------------------------------------------------
extern "C" void kernel_launch(void* const* d_in, const int* in_sizes, int n_in,
                              void* d_out, int out_size, void* d_ws, size_t ws_size,
                              hipStream_t stream) {
  const float* h   = (const float*)d_in[0];  // (8,2048,128) f32
  const float* adj = (const float*)d_in[1];  // (8,2048,2048) f32 {0,1}
  const float* Ws  = (const float*)d_in[2];  // (128,128) f32
  const float* bs  = (const float*)d_in[3];  // (128,) f32
  const float* Wn  = (const float*)d_in[4];  // (128,128) f32
  const float* bn  = (const float*)d_in[5];  // (128,) f32
  float* out = (float*)d_out;

  (void)in_sizes; (void)n_in; (void)out_size; (void)d_ws; (void)ws_size;

  sage_fused_kernel<<<dim3(BATCH * NNODE / 16), dim3(256), 0, stream>>>(
      h, adj, Ws, bs, Wn, bn, out);
}

// Round 8
// 329.035 us; speedup vs baseline: 1.7274x; 1.7274x over previous
//
#include <hip/hip_runtime.h>

typedef unsigned short u16;
typedef unsigned int u32;
typedef unsigned long long u64;

#define BATCH 8
#define NNODE 2048
#define FEAT  128

// ---------------------------------------------------------------------------
// Kernel 1: sparse aggregation. agg[row] = (sum_j adj[row][j] * h[j]) / N.
// adj is binary with ~32 nonzeros per 2048-row -> skip the zeros.
// One wave per output row; lane l holds features 2l, 2l+1 (float2 acc).
// Scan the adj row 64 elements at a time (1 f32/lane, coalesced 256B),
// __ballot the nonzeros (wave-uniform 64-bit mask), iterate set bits:
// broadcast the adj value via __shfl (paranoia: exact binarity not assumed),
// gather h[j] as float2/lane (coalesced 512B, L2-hot since h is 8 MB).
// No LDS at all -> max occupancy to hide gather latency.
// ---------------------------------------------------------------------------
__global__ __launch_bounds__(256) void agg_sparse_kernel(
    const float* __restrict__ adj,  // (B, N, N) f32 {0,1}
    const float* __restrict__ h,    // (B, N, F) f32
    float* __restrict__ agg)        // (B*N, F) f32 workspace
{
  const int tid = threadIdx.x;
  const int l = tid & 63;
  const int w = tid >> 6;
  const int row = blockIdx.x * 4 + w;     // 0 .. 16383
  const int b = row >> 11;
  const float* arow = adj + (size_t)row * NNODE;
  const float* hB   = h + (size_t)b * NNODE * FEAT;

  float ax = 0.0f, ay = 0.0f;

  float a = arow[l];                       // chunk 0 in flight
  for (int c = 0; c < 32; c++) {
    float an = (c < 31) ? arow[(c + 1) * 64 + l] : 0.0f;  // prefetch next
    u64 m = __ballot(a != 0.0f);
    const int jb = c * 64;
    while (m) {
      int s = (int)__builtin_ctzll(m);
      m &= m - 1;
      float av = __shfl(a, s);             // broadcast adj value (1.0)
      const float2 hv = *(const float2*)(hB + (size_t)(jb + s) * FEAT + 2 * l);
      ax += av * hv.x;
      ay += av * hv.y;
    }
    a = an;
  }

  const float invN = 1.0f / (float)NNODE;
  float2 res;
  res.x = ax * invN;
  res.y = ay * invN;
  *(float2*)(agg + (size_t)row * FEAT + 2 * l) = res;
}

// ---------------------------------------------------------------------------
// Kernel 2: out = L2normalize(relu(h@Ws + agg@Wn + bs + bn)).
// Proven phase-2 structure from the passing r7 kernel, agg read from ws.
// Block = 256 threads handles 16 rows: thread t -> feature pair fp = t&63,
// row group rg = t>>6 (rows rg*4..rg*4+3). W reads amortized over 16 rows.
// ---------------------------------------------------------------------------
__global__ __launch_bounds__(256) void linear_kernel(
    const float* __restrict__ h,    // (B*N, F) f32
    const float* __restrict__ agg,  // (B*N, F) f32
    const float* __restrict__ Ws,   // (F, F) f32
    const float* __restrict__ bs,   // (F,) f32
    const float* __restrict__ Wn,   // (F, F) f32
    const float* __restrict__ bn,   // (F,) f32
    float* __restrict__ out)        // (B*N, F) f32
{
  __shared__ float sOut[16 * 128];  // 8 KB
  __shared__ float sInv[16];

  const int tid = threadIdx.x;
  const int fp = tid & 63;
  const int rg = tid >> 6;
  const int r0 = blockIdx.x * 16;

  float o[4][2];
#pragma unroll
  for (int rr = 0; rr < 4; rr++) { o[rr][0] = 0.0f; o[rr][1] = 0.0f; }

  const float2* WsU = (const float2*)Ws;
  const float2* WnU = (const float2*)Wn;
  for (int k = 0; k < 128; k++) {
    float2 wsv = WsU[k * 64 + fp];
    float2 wnv = WnU[k * 64 + fp];
#pragma unroll
    for (int rr = 0; rr < 4; rr++) {
      size_t ridx = (size_t)(r0 + rg * 4 + rr) * FEAT + k;
      float hv = h[ridx];       // wave-uniform broadcast load
      float gv = agg[ridx];
      o[rr][0] += hv * wsv.x + gv * wnv.x;
      o[rr][1] += hv * wsv.y + gv * wnv.y;
    }
  }

  // bias + relu, stash to LDS for row L2-norm reduction
  float bias0 = bs[fp * 2 + 0] + bn[fp * 2 + 0];
  float bias1 = bs[fp * 2 + 1] + bn[fp * 2 + 1];
#pragma unroll
  for (int rr = 0; rr < 4; rr++) {
    float v0 = o[rr][0] + bias0; if (v0 < 0.0f) v0 = 0.0f;
    float v1 = o[rr][1] + bias1; if (v1 < 0.0f) v1 = 0.0f;
    o[rr][0] = v0; o[rr][1] = v1;
    sOut[(rg * 4 + rr) * 128 + fp * 2 + 0] = v0;
    sOut[(rg * 4 + rr) * 128 + fp * 2 + 1] = v1;
  }
  __syncthreads();
  if (tid < 16) {
    float s = 0.0f;
    for (int i = 0; i < 128; i++) {
      int ii = (i + tid * 8) & 127;          // stagger LDS banks
      float v = sOut[tid * 128 + ii];
      s += v * v;
    }
    float nrm = sqrtf(s);
    if (nrm < 1e-12f) nrm = 1e-12f;
    sInv[tid] = 1.0f / nrm;
  }
  __syncthreads();

  float2* outU = (float2*)(out + (size_t)r0 * FEAT);
#pragma unroll
  for (int rr = 0; rr < 4; rr++) {
    int r = rg * 4 + rr;
    float scl = sInv[r];
    float2 pv;
    pv.x = o[rr][0] * scl;
    pv.y = o[rr][1] * scl;
    outU[r * 64 + fp] = pv;
  }
}

// ---------------------------------------------------------------------------
extern "C" void kernel_launch(void* const* d_in, const int* in_sizes, int n_in,
                              void* d_out, int out_size, void* d_ws, size_t ws_size,
                              hipStream_t stream) {
  const float* h   = (const float*)d_in[0];  // (8,2048,128) f32
  const float* adj = (const float*)d_in[1];  // (8,2048,2048) f32 {0,1}
  const float* Ws  = (const float*)d_in[2];  // (128,128) f32
  const float* bs  = (const float*)d_in[3];  // (128,) f32
  const float* Wn  = (const float*)d_in[4];  // (128,128) f32
  const float* bn  = (const float*)d_in[5];  // (128,) f32
  float* out = (float*)d_out;
  float* agg = (float*)d_ws;                 // 8 MiB f32 scratch

  (void)in_sizes; (void)n_in; (void)out_size; (void)ws_size;

  agg_sparse_kernel<<<dim3(BATCH * NNODE / 4), dim3(256), 0, stream>>>(adj, h, agg);
  linear_kernel<<<dim3(BATCH * NNODE / 16), dim3(256), 0, stream>>>(
      h, agg, Ws, bs, Wn, bn, out);
}

// Round 9
// 248.813 us; speedup vs baseline: 2.2843x; 1.3224x over previous
//
#include <hip/hip_runtime.h>

typedef unsigned short u16;
typedef unsigned int u32;
typedef unsigned long long u64;

#define BATCH 8
#define NNODE 2048
#define FEAT  128

// ---------------------------------------------------------------------------
// Kernel 1: sparse aggregation. agg[row] = (sum_j adj[row][j] * h[j]) / N.
// adj is binary, ~32 nonzeros per 2048-row. One wave per row; lane l holds
// features 2l,2l+1. v2: the whole 8KB adj row is loaded UPFRONT as 8
// independent float4 loads (MLP=8, vs 1-deep prefetch in v1 which measured
// only 1.4 TB/s). Then per 64-element group: ballot, iterate set bits,
// gather h[j] (float2/lane, coalesced 512B, L2-hot: h is 1MB/batch).
// Lane l's float4 #i covers adj elements i*256 + 4l .. +3, so mask bit s of
// component c maps to column j = i*256 + 4s + c.
// ---------------------------------------------------------------------------
__device__ __forceinline__ void agg_group(float a, int jbase, int l2,
                                          const float* __restrict__ hB,
                                          float& ax, float& ay) {
  u64 m = __ballot(a != 0.0f);
  while (m) {
    int s = (int)__builtin_ctzll(m);
    m &= m - 1;
    float av = __shfl(a, s);              // adj value broadcast (1.0)
    const float2 hv = *(const float2*)(hB + (size_t)(jbase + 4 * s) * FEAT + l2);
    ax += av * hv.x;
    ay += av * hv.y;
  }
}

__global__ __launch_bounds__(256) void agg_sparse_kernel(
    const float* __restrict__ adj,  // (B, N, N) f32 {0,1}
    const float* __restrict__ h,    // (B, N, F) f32
    float* __restrict__ agg)        // (B*N, F) f32 workspace
{
  const int tid = threadIdx.x;
  const int l = tid & 63;
  const int w = tid >> 6;
  const int row = blockIdx.x * 4 + w;     // 0 .. 16383
  const int b = row >> 11;
  const float* arow = adj + (size_t)row * NNODE;
  const float* hB   = h + (size_t)b * NNODE * FEAT;
  const int l2 = 2 * l;

  float4 v[8];
#pragma unroll
  for (int i = 0; i < 8; i++)            // 8 loads all in flight at once
    v[i] = *(const float4*)(arow + i * 256 + l * 4);

  float ax = 0.0f, ay = 0.0f;
#pragma unroll
  for (int i = 0; i < 8; i++) {
    agg_group(v[i].x, i * 256 + 0, l2, hB, ax, ay);
    agg_group(v[i].y, i * 256 + 1, l2, hB, ax, ay);
    agg_group(v[i].z, i * 256 + 2, l2, hB, ax, ay);
    agg_group(v[i].w, i * 256 + 3, l2, hB, ax, ay);
  }

  const float invN = 1.0f / (float)NNODE;
  float2 res;
  res.x = ax * invN;
  res.y = ay * invN;
  *(float2*)(agg + (size_t)row * FEAT + l2) = res;
}

// ---------------------------------------------------------------------------
// Kernel 2: tiled GEMM + epilogue.
// C[16384,128] = A[16384,256] @ B[256,128], A = [h | agg] (k-concat),
// B = [Ws ; Wn] (row-stacked), then bias+relu+row-L2-normalize.
// Block: 256 thr, tile M=32 x N=128, K-tile=64 (4 tiles: h cols 0-63, 64-127,
// agg cols 0-63, 64-127). A staged k-major in LDS (pitch 34: even -> 8B
// aligned b64 reads, banks (2k+2rg)%32 conflict-free). B staged row-major
// (pitch 132: 16B-aligned b128; stride-8 tx reads are 4-way = 1.58x, minor).
// Thread = 2 rows x 8 cols: per k, 1 b64 + 2 b128 LDS reads vs 16 FMA.
// NO global loads in the k-loop (v1's fatal flaw: 8 serialized L2 broadcasts
// per k -> VALUBusy 12.6%, 100us for a 6.8us-floor GEMM).
// Row L2-norm: each row lives in 16 tx-lanes of one wave -> shfl_xor reduce.
// ---------------------------------------------------------------------------
#define APITCH 34
#define BPITCH 132

__global__ __launch_bounds__(256) void linear_kernel(
    const float* __restrict__ h,    // (B*N, F) f32
    const float* __restrict__ agg,  // (B*N, F) f32
    const float* __restrict__ Ws,   // (F, F) f32
    const float* __restrict__ bs,   // (F,) f32
    const float* __restrict__ Wn,   // (F, F) f32
    const float* __restrict__ bn,   // (F,) f32
    float* __restrict__ out)        // (B*N, F) f32
{
  __shared__ float sA[64 * APITCH];   // 8704 B,  [k][r]
  __shared__ float sB[64 * BPITCH];   // 33792 B, [k][c]

  const int tid = threadIdx.x;
  const int tx = tid & 15;          // col group: c = tx*8
  const int rg = tid >> 4;          // row group: r = r0 + rg*2 + {0,1}
  const int r0 = blockIdx.x * 32;

  float acc0[8], acc1[8];
#pragma unroll
  for (int j = 0; j < 8; j++) { acc0[j] = 0.0f; acc1[j] = 0.0f; }

  // staging index maps (computed once)
  const int arl = tid >> 3;         // A: local row 0..31
  const int aq  = tid & 7;          // A: k-quad 0..7 (covers k aq*4, +32)
  const int bkl = tid >> 2;         // B: local k 0..63
  const int bq  = tid & 3;          // B: col-f4 phase 0..3

  for (int t = 0; t < 4; t++) {
    const float* Asrc = (t < 2) ? h : agg;
    const int akb = (t & 1) * 64;                    // k offset within source
    const float* Bsrc = (t < 2) ? (Ws + (size_t)(t * 64) * FEAT)
                                : (Wn + (size_t)((t - 2) * 64) * FEAT);
    __syncthreads();   // previous tile's LDS reads complete
    // ---- stage A: 32 rows x 64 k, transposed to k-major ----
    {
      const float* src = Asrc + (size_t)(r0 + arl) * FEAT + akb + aq * 4;
      float4 v0 = *(const float4*)(src);
      float4 v1 = *(const float4*)(src + 32);
      sA[(aq * 4 + 0) * APITCH + arl] = v0.x;
      sA[(aq * 4 + 1) * APITCH + arl] = v0.y;
      sA[(aq * 4 + 2) * APITCH + arl] = v0.z;
      sA[(aq * 4 + 3) * APITCH + arl] = v0.w;
      sA[(aq * 4 + 32) * APITCH + arl] = v1.x;
      sA[(aq * 4 + 33) * APITCH + arl] = v1.y;
      sA[(aq * 4 + 34) * APITCH + arl] = v1.z;
      sA[(aq * 4 + 35) * APITCH + arl] = v1.w;
    }
    // ---- stage B: 64 k x 128 c ----
    {
      const float* src = Bsrc + (size_t)bkl * FEAT;
#pragma unroll
      for (int j = 0; j < 8; j++) {
        int cw = (bq + 4 * j) * 4;
        *(float4*)&sB[bkl * BPITCH + cw] = *(const float4*)(src + cw);
      }
    }
    __syncthreads();
    // ---- compute ----
#pragma unroll 8
    for (int k = 0; k < 64; k++) {
      float2 av = *(const float2*)&sA[k * APITCH + rg * 2];
      float4 b0 = *(const float4*)&sB[k * BPITCH + tx * 8];
      float4 b1 = *(const float4*)&sB[k * BPITCH + tx * 8 + 4];
      acc0[0] += av.x * b0.x;  acc1[0] += av.y * b0.x;
      acc0[1] += av.x * b0.y;  acc1[1] += av.y * b0.y;
      acc0[2] += av.x * b0.z;  acc1[2] += av.y * b0.z;
      acc0[3] += av.x * b0.w;  acc1[3] += av.y * b0.w;
      acc0[4] += av.x * b1.x;  acc1[4] += av.y * b1.x;
      acc0[5] += av.x * b1.y;  acc1[5] += av.y * b1.y;
      acc0[6] += av.x * b1.z;  acc1[6] += av.y * b1.z;
      acc0[7] += av.x * b1.w;  acc1[7] += av.y * b1.w;
    }
  }

  // ---- epilogue: bias + relu + row L2-norm (shfl over 16 tx lanes) ----
  float4 bsv0 = *(const float4*)(bs + tx * 8);
  float4 bsv1 = *(const float4*)(bs + tx * 8 + 4);
  float4 bnv0 = *(const float4*)(bn + tx * 8);
  float4 bnv1 = *(const float4*)(bn + tx * 8 + 4);
  float bias[8];
  bias[0] = bsv0.x + bnv0.x; bias[1] = bsv0.y + bnv0.y;
  bias[2] = bsv0.z + bnv0.z; bias[3] = bsv0.w + bnv0.w;
  bias[4] = bsv1.x + bnv1.x; bias[5] = bsv1.y + bnv1.y;
  bias[6] = bsv1.z + bnv1.z; bias[7] = bsv1.w + bnv1.w;

  float ss0 = 0.0f, ss1 = 0.0f;
#pragma unroll
  for (int j = 0; j < 8; j++) {
    float v0 = acc0[j] + bias[j]; if (v0 < 0.0f) v0 = 0.0f;
    float v1 = acc1[j] + bias[j]; if (v1 < 0.0f) v1 = 0.0f;
    acc0[j] = v0; acc1[j] = v1;
    ss0 += v0 * v0;
    ss1 += v1 * v1;
  }
  ss0 += __shfl_xor(ss0, 1); ss1 += __shfl_xor(ss1, 1);
  ss0 += __shfl_xor(ss0, 2); ss1 += __shfl_xor(ss1, 2);
  ss0 += __shfl_xor(ss0, 4); ss1 += __shfl_xor(ss1, 4);
  ss0 += __shfl_xor(ss0, 8); ss1 += __shfl_xor(ss1, 8);
  float n0 = sqrtf(ss0); if (n0 < 1e-12f) n0 = 1e-12f;
  float n1 = sqrtf(ss1); if (n1 < 1e-12f) n1 = 1e-12f;
  float s0 = 1.0f / n0, s1 = 1.0f / n1;

  float* orow0 = out + (size_t)(r0 + rg * 2 + 0) * FEAT + tx * 8;
  float* orow1 = out + (size_t)(r0 + rg * 2 + 1) * FEAT + tx * 8;
  float4 w0, w1;
  w0.x = acc0[0] * s0; w0.y = acc0[1] * s0; w0.z = acc0[2] * s0; w0.w = acc0[3] * s0;
  w1.x = acc0[4] * s0; w1.y = acc0[5] * s0; w1.z = acc0[6] * s0; w1.w = acc0[7] * s0;
  *(float4*)(orow0) = w0;
  *(float4*)(orow0 + 4) = w1;
  w0.x = acc1[0] * s1; w0.y = acc1[1] * s1; w0.z = acc1[2] * s1; w0.w = acc1[3] * s1;
  w1.x = acc1[4] * s1; w1.y = acc1[5] * s1; w1.z = acc1[6] * s1; w1.w = acc1[7] * s1;
  *(float4*)(orow1) = w0;
  *(float4*)(orow1 + 4) = w1;
}

// ---------------------------------------------------------------------------
extern "C" void kernel_launch(void* const* d_in, const int* in_sizes, int n_in,
                              void* d_out, int out_size, void* d_ws, size_t ws_size,
                              hipStream_t stream) {
  const float* h   = (const float*)d_in[0];  // (8,2048,128) f32
  const float* adj = (const float*)d_in[1];  // (8,2048,2048) f32 {0,1}
  const float* Ws  = (const float*)d_in[2];  // (128,128) f32
  const float* bs  = (const float*)d_in[3];  // (128,) f32
  const float* Wn  = (const float*)d_in[4];  // (128,128) f32
  const float* bn  = (const float*)d_in[5];  // (128,) f32
  float* out = (float*)d_out;
  float* agg = (float*)d_ws;                 // 8 MiB f32 scratch

  (void)in_sizes; (void)n_in; (void)out_size; (void)ws_size;

  agg_sparse_kernel<<<dim3(BATCH * NNODE / 4), dim3(256), 0, stream>>>(adj, h, agg);
  linear_kernel<<<dim3(BATCH * NNODE / 32), dim3(256), 0, stream>>>(
      h, agg, Ws, bs, Wn, bn, out);
}

// Round 10
// 233.249 us; speedup vs baseline: 2.4367x; 1.0667x over previous
//
#include <hip/hip_runtime.h>

typedef unsigned short u16;
typedef unsigned int u32;
typedef unsigned long long u64;

#define BATCH 8
#define NNODE 2048
#define FEAT  128
#define CAP   320   // index-list capacity per row; nnz ~ Binom(2048,1/64):
                    // mean 32, sigma 5.6 -> P(nnz>320) ~ 0. Fallback keeps
                    // correctness anyway.

// ---------------------------------------------------------------------------
// Kernel 1: sparse aggregation, v3 (two-phase index-list gather).
// agg[row] = (sum_j adj[row][j] * h[j]) / N, adj binary ~32 nnz/row.
// One wave per row, lane l owns features 2l,2l+1.
// v2's flaw: while(ballot) gather is a serial chain (ctz->shfl->load->FMA,
// ~300cy per nnz exposed). v3 phase A: scan adj row (8x float4/lane, all in
// flight), compress nonzero COLUMN INDICES to LDS via ballot+mbcnt prefix --
// pure VALU, no dependent loads. Phase B: read 8 indices per step (wave-
// uniform LDS broadcast) and issue 8 INDEPENDENT float2 h-gathers -> 8
// outstanding loads, latency/8. Compute becomes negligible vs the 134MB
// adj HBM stream (21us floor).
// ---------------------------------------------------------------------------
__global__ __launch_bounds__(256) void agg_sparse_kernel(
    const float* __restrict__ adj,  // (B, N, N) f32 {0,1}
    const float* __restrict__ h,    // (B, N, F) f32
    float* __restrict__ agg)        // (B*N, F) f32 workspace
{
  __shared__ int sIdx[4][CAP];
  const int tid = threadIdx.x;
  const int l = tid & 63;
  const int w = tid >> 6;
  const int row = blockIdx.x * 4 + w;     // 0 .. 16383
  const int b = row >> 11;
  const float* arow = adj + (size_t)row * NNODE;
  const float* hB   = h + (size_t)b * NNODE * FEAT;
  const int l2 = 2 * l;
  int* idx = sIdx[w];

  float4 v[8];
#pragma unroll
  for (int i = 0; i < 8; i++)            // whole 8KB adj row in flight
    v[i] = *(const float4*)(arow + i * 256 + l * 4);

  float ax = 0.0f, ay = 0.0f;
  int base = 0;

  // ---- phase A: compress nonzero column indices to LDS (no loads) ----
#pragma unroll
  for (int i = 0; i < 8; i++) {
#pragma unroll
    for (int c = 0; c < 4; c++) {
      float a = (c == 0) ? v[i].x : (c == 1) ? v[i].y : (c == 2) ? v[i].z : v[i].w;
      bool nz = (a != 0.0f);
      u64 m = __ballot(nz);
      if (m == 0) continue;               // ~37% of groups empty (Poisson 1)
      int pre = __builtin_amdgcn_mbcnt_hi(
          (u32)(m >> 32), __builtin_amdgcn_mbcnt_lo((u32)m, 0));
      int pos = base + pre;
      if (nz && pos < CAP) idx[pos] = i * 256 + 4 * l + c;
      // overflow fallback (p ~ 0): immediate serial gather for dropped bits
      u64 md = __ballot(nz && pos >= CAP);
      while (md) {
        int s = (int)__builtin_ctzll(md);
        md &= md - 1;
        const float2 g = *(const float2*)(hB + (size_t)(i * 256 + 4 * s + c) * FEAT + l2);
        ax += g.x; ay += g.y;
      }
      base += (int)__builtin_popcountll(m);
    }
  }
  const int n = (base < CAP) ? base : CAP;

  // ---- phase B: batched gathers, 8 independent loads per step ----
  int i = 0;
  for (; i + 8 <= n; i += 8) {
    int4 j0 = *(const int4*)&idx[i];      // wave-uniform -> LDS broadcast
    int4 j1 = *(const int4*)&idx[i + 4];
    float2 g0 = *(const float2*)(hB + (size_t)j0.x * FEAT + l2);
    float2 g1 = *(const float2*)(hB + (size_t)j0.y * FEAT + l2);
    float2 g2 = *(const float2*)(hB + (size_t)j0.z * FEAT + l2);
    float2 g3 = *(const float2*)(hB + (size_t)j0.w * FEAT + l2);
    float2 g4 = *(const float2*)(hB + (size_t)j1.x * FEAT + l2);
    float2 g5 = *(const float2*)(hB + (size_t)j1.y * FEAT + l2);
    float2 g6 = *(const float2*)(hB + (size_t)j1.z * FEAT + l2);
    float2 g7 = *(const float2*)(hB + (size_t)j1.w * FEAT + l2);
    ax += ((g0.x + g1.x) + (g2.x + g3.x)) + ((g4.x + g5.x) + (g6.x + g7.x));
    ay += ((g0.y + g1.y) + (g2.y + g3.y)) + ((g4.y + g5.y) + (g6.y + g7.y));
  }
  for (; i < n; i++) {
    int j = idx[i];
    const float2 g = *(const float2*)(hB + (size_t)j * FEAT + l2);
    ax += g.x; ay += g.y;
  }

  const float invN = 1.0f / (float)NNODE;
  float2 res;
  res.x = ax * invN;
  res.y = ay * invN;
  *(float2*)(agg + (size_t)row * FEAT + l2) = res;
}

// ---------------------------------------------------------------------------
// Kernel 2: tiled GEMM + epilogue, v3 (register-blocked 4x8).
// C[16384,128] = [h|agg] @ [Ws;Wn] (K=256), bias+relu+row-L2-norm.
// Block: 256 thr, tile M=64 x N=128, K-tile 64, grid 256 (1 block/CU).
// Thread = 4 rows x 8 cols: per k, 32 FMA vs 1 b128 A-read (4-address
// broadcast across tx) + 2 b128 B-reads -> ~2.7x less LDS traffic per FLOP
// than v2 (which was LDS-BW bound at ~2560B per 16 FMA). VALU-bound target.
// ---------------------------------------------------------------------------
#define APITCH 68
#define BPITCH 132

__global__ __launch_bounds__(256) void linear_kernel(
    const float* __restrict__ h,    // (B*N, F) f32
    const float* __restrict__ agg,  // (B*N, F) f32
    const float* __restrict__ Ws,   // (F, F) f32
    const float* __restrict__ bs,   // (F,) f32
    const float* __restrict__ Wn,   // (F, F) f32
    const float* __restrict__ bn,   // (F,) f32
    float* __restrict__ out)        // (B*N, F) f32
{
  __shared__ float sA[64 * APITCH];   // 17.0 KB, [k][r] k-major
  __shared__ float sB[64 * BPITCH];   // 33.8 KB, [k][c]

  const int tid = threadIdx.x;
  const int tx = tid & 15;          // col group: c = tx*8
  const int rg = tid >> 4;          // row group: r = r0 + rg*4 + 0..3
  const int r0 = blockIdx.x * 64;

  float acc[4][8];
#pragma unroll
  for (int r = 0; r < 4; r++)
#pragma unroll
    for (int c = 0; c < 8; c++) acc[r][c] = 0.0f;

  const int arl = tid >> 2;         // A staging: local row 0..63
  const int aq  = tid & 3;          // A staging: k-phase 0..3
  const int bkl = tid >> 2;         // B staging: local k 0..63
  const int bq  = tid & 3;          // B staging: col-f4 phase 0..3

  for (int t = 0; t < 4; t++) {
    const float* Asrc = ((t < 2) ? h : agg) + (size_t)(t & 1) * 64;
    const float* Bsrc = (t < 2) ? (Ws + (size_t)(t * 64) * FEAT)
                                : (Wn + (size_t)((t - 2) * 64) * FEAT);
    __syncthreads();   // previous tile's LDS reads complete
    // ---- stage A: 64 rows x 64 k, transposed to k-major ----
    {
      const float* src = Asrc + (size_t)(r0 + arl) * FEAT + aq * 4;
#pragma unroll
      for (int ii = 0; ii < 4; ii++) {
        float4 vv = *(const float4*)(src + ii * 16);
        int kk = aq * 4 + ii * 16;
        sA[(kk + 0) * APITCH + arl] = vv.x;
        sA[(kk + 1) * APITCH + arl] = vv.y;
        sA[(kk + 2) * APITCH + arl] = vv.z;
        sA[(kk + 3) * APITCH + arl] = vv.w;
      }
    }
    // ---- stage B: 64 k x 128 c ----
    {
      const float* src = Bsrc + (size_t)bkl * FEAT;
#pragma unroll
      for (int j = 0; j < 8; j++) {
        int cw = (bq + 4 * j) * 4;
        *(float4*)&sB[bkl * BPITCH + cw] = *(const float4*)(src + cw);
      }
    }
    __syncthreads();
    // ---- compute ----
#pragma unroll 4
    for (int k = 0; k < 64; k++) {
      float4 av = *(const float4*)&sA[k * APITCH + rg * 4];
      float4 b0 = *(const float4*)&sB[k * BPITCH + tx * 8];
      float4 b1 = *(const float4*)&sB[k * BPITCH + tx * 8 + 4];
      const float a[4] = {av.x, av.y, av.z, av.w};
      const float bb[8] = {b0.x, b0.y, b0.z, b0.w, b1.x, b1.y, b1.z, b1.w};
#pragma unroll
      for (int r = 0; r < 4; r++)
#pragma unroll
        for (int c = 0; c < 8; c++)
          acc[r][c] += a[r] * bb[c];
    }
  }

  // ---- epilogue: bias + relu + row L2-norm (shfl over 16 tx lanes) ----
  float4 bsv0 = *(const float4*)(bs + tx * 8);
  float4 bsv1 = *(const float4*)(bs + tx * 8 + 4);
  float4 bnv0 = *(const float4*)(bn + tx * 8);
  float4 bnv1 = *(const float4*)(bn + tx * 8 + 4);
  float bias[8];
  bias[0] = bsv0.x + bnv0.x; bias[1] = bsv0.y + bnv0.y;
  bias[2] = bsv0.z + bnv0.z; bias[3] = bsv0.w + bnv0.w;
  bias[4] = bsv1.x + bnv1.x; bias[5] = bsv1.y + bnv1.y;
  bias[6] = bsv1.z + bnv1.z; bias[7] = bsv1.w + bnv1.w;

  float ss[4] = {0.f, 0.f, 0.f, 0.f};
#pragma unroll
  for (int r = 0; r < 4; r++)
#pragma unroll
    for (int c = 0; c < 8; c++) {
      float vv = acc[r][c] + bias[c];
      if (vv < 0.0f) vv = 0.0f;
      acc[r][c] = vv;
      ss[r] += vv * vv;
    }
#pragma unroll
  for (int r = 0; r < 4; r++) {
    float s = ss[r];
    s += __shfl_xor(s, 1);
    s += __shfl_xor(s, 2);
    s += __shfl_xor(s, 4);
    s += __shfl_xor(s, 8);
    float nrm = sqrtf(s);
    if (nrm < 1e-12f) nrm = 1e-12f;
    ss[r] = 1.0f / nrm;
  }
#pragma unroll
  for (int r = 0; r < 4; r++) {
    float* orow = out + (size_t)(r0 + rg * 4 + r) * FEAT + tx * 8;
    float4 w0, w1;
    w0.x = acc[r][0] * ss[r]; w0.y = acc[r][1] * ss[r];
    w0.z = acc[r][2] * ss[r]; w0.w = acc[r][3] * ss[r];
    w1.x = acc[r][4] * ss[r]; w1.y = acc[r][5] * ss[r];
    w1.z = acc[r][6] * ss[r]; w1.w = acc[r][7] * ss[r];
    *(float4*)(orow) = w0;
    *(float4*)(orow + 4) = w1;
  }
}

// ---------------------------------------------------------------------------
extern "C" void kernel_launch(void* const* d_in, const int* in_sizes, int n_in,
                              void* d_out, int out_size, void* d_ws, size_t ws_size,
                              hipStream_t stream) {
  const float* h   = (const float*)d_in[0];  // (8,2048,128) f32
  const float* adj = (const float*)d_in[1];  // (8,2048,2048) f32 {0,1}
  const float* Ws  = (const float*)d_in[2];  // (128,128) f32
  const float* bs  = (const float*)d_in[3];  // (128,) f32
  const float* Wn  = (const float*)d_in[4];  // (128,128) f32
  const float* bn  = (const float*)d_in[5];  // (128,) f32
  float* out = (float*)d_out;
  float* agg = (float*)d_ws;                 // 8 MiB f32 scratch

  (void)in_sizes; (void)n_in; (void)out_size; (void)ws_size;

  agg_sparse_kernel<<<dim3(BATCH * NNODE / 4), dim3(256), 0, stream>>>(adj, h, agg);
  linear_kernel<<<dim3(BATCH * NNODE / 64), dim3(256), 0, stream>>>(
      h, agg, Ws, bs, Wn, bn, out);
}